// Round 1
// baseline (512.658 us; speedup 1.0000x reference)
//
#include <hip/hip_runtime.h>
#include <hip/hip_bf16.h>

// Problem constants
#define NB    8      // batch
#define NG    64     // c_inp groups (g)
#define NCI   16     // conv in channels (ci)
#define NC0   16     // conv out channels (c0)
#define NJ    64     // c_out (j)
#define IH    64
#define IW    64
#define OH    62
#define OW    62
#define IPIX  4096   // 64*64
#define OPIX  3844   // 62*62

__device__ __forceinline__ float bf2f(unsigned short u) {
    union { unsigned int i; float f; } v;
    v.i = ((unsigned int)u) << 16;
    return v.f;
}

// ---------------------------------------------------------------------------
// Kernel 1: build Wm[g][j] (64x64) from TT cores.
// Wm[g,j] = sum_{r1,r2} core0[0,i1,j1,r1] * core1[r1,i2,j2,r2] * core2[r2,i3,j3,0]
// g = i1*16+i2*4+i3, j = j1*16+j2*4+j3
// ---------------------------------------------------------------------------
__global__ __launch_bounds__(64) void wm_kernel(const float* __restrict__ core0,
                                                const float* __restrict__ core1,
                                                const float* __restrict__ core2,
                                                float* __restrict__ Wm) {
    int g = threadIdx.x;
    int i1 = g >> 4, i2 = (g >> 2) & 3, i3 = g & 3;
    for (int j = 0; j < NJ; ++j) {
        int j1 = j >> 4, j2 = (j >> 2) & 3, j3 = j & 3;
        float s = 0.f;
        #pragma unroll
        for (int r1 = 0; r1 < 8; ++r1) {
            float a = core0[(i1 * 4 + j1) * 8 + r1];
            float t = 0.f;
            #pragma unroll
            for (int r2 = 0; r2 < 8; ++r2) {
                t += core1[((r1 * 4 + i2) * 4 + j2) * 8 + r2] *
                     core2[(r2 * 4 + i3) * 4 + j3];
            }
            s += a * t;
        }
        Wm[g * NJ + j] = s;
    }
}

// ---------------------------------------------------------------------------
// Kernel 2: channel mix.  Z[b][j][ci][p] = sum_g Wm[g][j] * x[b, g*16+ci, p]
// Z stored bf16. One thread per (b,ci,p), 64 j-accumulators in registers.
// grid = 8*16*16 = 2048 blocks of 256.
// ---------------------------------------------------------------------------
__global__ __launch_bounds__(256) void mix_kernel(const float* __restrict__ x,
                                                  const float* __restrict__ Wm,
                                                  __hip_bfloat16* __restrict__ Z) {
    __shared__ float4 wlds[NG * 16];  // Wm rows as float4 (j-contiguous)
    const float4* wg = (const float4*)Wm;
    for (int i = threadIdx.x; i < NG * 16; i += 256) wlds[i] = wg[i];
    __syncthreads();

    int blk  = blockIdx.x;
    int pblk = blk & 15;
    int ci   = (blk >> 4) & 15;
    int b    = blk >> 8;
    int p    = pblk * 256 + threadIdx.x;

    float acc[NJ];
    #pragma unroll
    for (int j = 0; j < NJ; ++j) acc[j] = 0.f;

    const float* xb = x + ((size_t)(b * NG) * NCI + ci) * IPIX + p;
    for (int g = 0; g < NG; ++g) {
        float xv = xb[(size_t)g * NCI * IPIX];
        #pragma unroll
        for (int j4 = 0; j4 < 16; ++j4) {
            float4 w = wlds[g * 16 + j4];
            acc[j4 * 4 + 0] += w.x * xv;
            acc[j4 * 4 + 1] += w.y * xv;
            acc[j4 * 4 + 2] += w.z * xv;
            acc[j4 * 4 + 3] += w.w * xv;
        }
    }

    __hip_bfloat16* zb = Z + ((size_t)(b * NG) * NCI + ci) * IPIX + p;
    #pragma unroll
    for (int j = 0; j < NJ; ++j)
        zb[(size_t)j * NCI * IPIX] = __float2bfloat16(acc[j]);
}

// ---------------------------------------------------------------------------
// Kernel 3: per-(b,j) 16->16 3x3 VALID conv from Z, + bias, write out.
// out[((b*16+c0)*3844 + y*62 + x)*64 + j]
// Lane = j (coalesced stores). Block = (b, y, xhalf); 4 waves, each wave
// covers 2 x-groups of 4 output pixels. Thread computes all 16 c0.
// grid = 8*62*2 = 992 blocks of 256.
// ---------------------------------------------------------------------------
__global__ __launch_bounds__(256) void conv_kernel(const __hip_bfloat16* __restrict__ Z,
                                                   const float* __restrict__ K,
                                                   const float* __restrict__ bias,
                                                   float* __restrict__ out) {
    __shared__ float klds[NCI * 9 * NC0];  // [ci][tap][c0]
    for (int i = threadIdx.x; i < NCI * 9 * NC0; i += 256) {
        int c0 = i & 15;
        int rest = i >> 4;
        int tap = rest % 9;
        int ci  = rest / 9;
        klds[i] = K[(c0 * NCI + ci) * 9 + tap];
    }
    __syncthreads();

    int blk = blockIdx.x;
    int xh  = blk & 1;
    int y   = (blk >> 1) % OH;
    int b   = blk / (OH * 2);
    int wv  = threadIdx.x >> 6;   // wave in block: 0..3
    int j   = threadIdx.x & 63;   // lane = j

    float bj = bias[j];
    const __hip_bfloat16* zb = Z + ((size_t)(b * NG + j) * NCI) * IPIX;

    for (int xi = 0; xi < 2; ++xi) {
        int xg = xh * 8 + wv * 2 + xi;   // 0..15
        int x0 = xg * 4;

        float acc[NC0 * 4];  // [c0][px]
        #pragma unroll
        for (int i = 0; i < NC0 * 4; ++i) acc[i] = bj;

        for (int ci = 0; ci < NCI; ++ci) {
            const __hip_bfloat16* zp = zb + (size_t)ci * IPIX;
            float r[3][8];
            #pragma unroll
            for (int dy = 0; dy < 3; ++dy) {
                const unsigned short* up = (const unsigned short*)(zp + (y + dy) * IW);
                ushort4 a = *(const ushort4*)(up + x0);
                int c2 = (x0 >= 60) ? 60 : x0 + 4;  // clamp (values only feed masked px)
                ushort4 q = *(const ushort4*)(up + c2);
                r[dy][0] = bf2f(a.x); r[dy][1] = bf2f(a.y);
                r[dy][2] = bf2f(a.z); r[dy][3] = bf2f(a.w);
                r[dy][4] = bf2f(q.x); r[dy][5] = bf2f(q.y);
                r[dy][6] = bf2f(q.z); r[dy][7] = bf2f(q.w);
            }
            #pragma unroll
            for (int dy = 0; dy < 3; ++dy) {
                #pragma unroll
                for (int dx = 0; dx < 3; ++dx) {
                    const float4* kp = (const float4*)&klds[((ci * 3 + dy) * 3 + dx) * NC0];
                    #pragma unroll
                    for (int c4 = 0; c4 < 4; ++c4) {
                        float4 kv = kp[c4];
                        #pragma unroll
                        for (int px = 0; px < 4; ++px) {
                            float zv = r[dy][px + dx];
                            acc[(c4 * 4 + 0) * 4 + px] += kv.x * zv;
                            acc[(c4 * 4 + 1) * 4 + px] += kv.y * zv;
                            acc[(c4 * 4 + 2) * 4 + px] += kv.z * zv;
                            acc[(c4 * 4 + 3) * 4 + px] += kv.w * zv;
                        }
                    }
                }
            }
        }

        #pragma unroll
        for (int c0 = 0; c0 < NC0; ++c0) {
            #pragma unroll
            for (int px = 0; px < 4; ++px) {
                int xx = x0 + px;
                if (xx < OW) {
                    out[(((size_t)(b * NC0 + c0) * OPIX) + y * OW + xx) * NJ + j] =
                        acc[c0 * 4 + px];
                }
            }
        }
    }
}

// ---------------------------------------------------------------------------
// Fallback (ws too small): naive fused, fp32 throughout. Correct but slow.
// One thread per (b,c0,pixel), 64 j accumulators.
// ---------------------------------------------------------------------------
__global__ __launch_bounds__(256) void fused_fallback(const float* __restrict__ x,
                                                      const float* __restrict__ K,
                                                      const float* __restrict__ Wm,
                                                      const float* __restrict__ bias,
                                                      float* __restrict__ out) {
    __shared__ float wlds[NG * NJ];
    __shared__ float klds[NCI * 9];
    int blk  = blockIdx.x;
    int pblk = blk & 15;
    int c0   = (blk >> 4) & 15;
    int b    = blk >> 8;
    for (int i = threadIdx.x; i < NG * NJ; i += 256) wlds[i] = Wm[i];
    for (int i = threadIdx.x; i < NCI * 9; i += 256) klds[i] = K[c0 * NCI * 9 + i];
    __syncthreads();

    int pix = pblk * 256 + threadIdx.x;
    if (pix >= OPIX) return;
    int y  = pix / OW;
    int xx = pix % OW;

    float acc[NJ];
    #pragma unroll
    for (int j = 0; j < NJ; ++j) acc[j] = 0.f;

    for (int g = 0; g < NG; ++g) {
        float c = 0.f;
        const float* xb = x + ((size_t)(b * NG + g) * NCI) * IPIX;
        for (int ci = 0; ci < NCI; ++ci) {
            #pragma unroll
            for (int dy = 0; dy < 3; ++dy) {
                #pragma unroll
                for (int dx = 0; dx < 3; ++dx) {
                    c += xb[ci * IPIX + (y + dy) * IW + (xx + dx)] *
                         klds[ci * 9 + dy * 3 + dx];
                }
            }
        }
        const float4* wp = (const float4*)&wlds[g * NJ];
        #pragma unroll
        for (int j4 = 0; j4 < 16; ++j4) {
            float4 w = wp[j4];
            acc[j4 * 4 + 0] += w.x * c;
            acc[j4 * 4 + 1] += w.y * c;
            acc[j4 * 4 + 2] += w.z * c;
            acc[j4 * 4 + 3] += w.w * c;
        }
    }
    #pragma unroll
    for (int j = 0; j < NJ; ++j) {
        out[(((size_t)(b * NC0 + c0) * OPIX) + pix) * NJ + j] = acc[j] + bias[j];
    }
}

extern "C" void kernel_launch(void* const* d_in, const int* in_sizes, int n_in,
                              void* d_out, int out_size, void* d_ws, size_t ws_size,
                              hipStream_t stream) {
    const float* x     = (const float*)d_in[0];
    const float* K     = (const float*)d_in[1];
    const float* core0 = (const float*)d_in[2];
    const float* core1 = (const float*)d_in[3];
    const float* core2 = (const float*)d_in[4];
    const float* bias  = (const float*)d_in[5];
    float* out = (float*)d_out;

    float* Wm = (float*)d_ws;
    const size_t z_off   = 16384;  // bytes reserved for Wm (needs 16KB)
    const size_t z_bytes = (size_t)NB * NJ * NCI * IPIX * sizeof(__hip_bfloat16);

    wm_kernel<<<1, 64, 0, stream>>>(core0, core1, core2, Wm);

    if (ws_size >= z_off + z_bytes + 256) {
        __hip_bfloat16* Z = (__hip_bfloat16*)((char*)d_ws + z_off);
        mix_kernel<<<NB * NCI * 16, 256, 0, stream>>>(x, Wm, Z);
        conv_kernel<<<NB * OH * 2, 256, 0, stream>>>(Z, K, bias, out);
    } else {
        fused_fallback<<<NB * NC0 * 16, 256, 0, stream>>>(x, K, Wm, bias, out);
    }
}

// Round 2
// 296.838 us; speedup vs baseline: 1.7271x; 1.7271x over previous
//
#include <hip/hip_runtime.h>
#include <hip/hip_bf16.h>

// Problem constants
#define NB    8      // batch
#define NG    64     // c_inp groups (g)
#define NCI   16     // conv in channels (ci)
#define NC0   16     // conv out channels (c0)
#define NJ    64     // c_out (j)
#define IH    64
#define IW    64
#define OH    62
#define OW    62
#define IPIX  4096   // 64*64
#define OPIX  3844   // 62*62

typedef __attribute__((ext_vector_type(8))) short  short8;
typedef __attribute__((ext_vector_type(4))) short  short4v;
typedef __attribute__((ext_vector_type(4))) float  float4v;

__device__ __forceinline__ unsigned short f2bf(float f) {
    unsigned int u = __builtin_bit_cast(unsigned int, f);
    unsigned int r = (u + 0x7fffu + ((u >> 16) & 1u)) >> 16;
    return (unsigned short)r;
}

// ---------------------------------------------------------------------------
// prep: blocks 0..7 build Wm B-fragments (bf16) for mix (jt = bi>>1, kh = bi&1)
//       block 8 builds conv A-fragments Kb (K padded to 160 contraction, bf16)
// Fragment convention (16x16x32 bf16): free index = lane&15, k = (lane>>4)*8+i.
// ---------------------------------------------------------------------------
__global__ __launch_bounds__(64) void prep_kernel(const float* __restrict__ K,
                                                  const float* __restrict__ c0_,
                                                  const float* __restrict__ c1_,
                                                  const float* __restrict__ c2_,
                                                  unsigned short* __restrict__ wmb,
                                                  unsigned short* __restrict__ kb) {
    int bi = blockIdx.x;
    int l  = threadIdx.x;
    if (bi < 8) {
        int jt = bi >> 1, kh = bi & 1;
        int j = jt * 16 + (l & 15);
        int j1 = j >> 4, j2 = (j >> 2) & 3, j3 = j & 3;
        for (int i = 0; i < 8; ++i) {
            int g = kh * 32 + (l >> 4) * 8 + i;
            int i1 = g >> 4, i2 = (g >> 2) & 3, i3 = g & 3;
            float s = 0.f;
            #pragma unroll
            for (int r1 = 0; r1 < 8; ++r1) {
                float a = c0_[(i1 * 4 + j1) * 8 + r1];
                float t = 0.f;
                #pragma unroll
                for (int r2 = 0; r2 < 8; ++r2) {
                    t += c1_[((r1 * 4 + i2) * 4 + j2) * 8 + r2] *
                         c2_[(r2 * 4 + i3) * 4 + j3];
                }
                s += a * t;
            }
            wmb[(bi * 64 + l) * 8 + i] = f2bf(s);
        }
    } else {
        int c0i = l & 15, q = l >> 4;
        for (int f = 0; f < 5; ++f) {
            int tap = f * 2 + (q >> 1);  // 0..9; 9 = zero pad
            for (int i = 0; i < 8; ++i) {
                int ci = (q & 1) * 8 + i;
                float v = (tap < 9) ? K[(c0i * 16 + ci) * 9 + tap] : 0.f;
                kb[(f * 64 + l) * 8 + i] = f2bf(v);
            }
        }
    }
}

// ---------------------------------------------------------------------------
// mix2: Z[b][p][j][ci] (bf16) = sum_g x[b,g,ci,p] * Wm[g,j]  via MFMA.
// Per pixel: D[m=ci(16)][n=j(16 per tile)] with K = g (64 = 2 frags).
// x staged in LDS as [p(32)][ci][g] bf16 with XOR bank swizzle.
// grid = 8 * 128 = 1024 blocks of 256.
// ---------------------------------------------------------------------------
__global__ __launch_bounds__(256) void mix2_kernel(const float* __restrict__ x,
                                                   const unsigned short* __restrict__ wmb,
                                                   unsigned short* __restrict__ Z) {
    __shared__ __align__(16) char smem[32 * 2048];  // 64 KB
    int t  = threadIdx.x;
    int b  = blockIdx.x >> 7;
    int p0 = (blockIdx.x & 127) * 32;

    // ---- stage x -> LDS [px][ci][g] bf16, swizzled ----
    int px = t & 31, grp = t >> 5;
    const float* xb = x + (size_t)b * 1024 * IPIX + p0 + px;
    for (int it = 0; it < 32; ++it) {
        int qd = it * 8 + grp;        // 0..255 channel-quads
        int gq = qd & 15, ci = qd >> 4;
        int g0 = gq * 4;
        const float* xp = xb + (size_t)(g0 * 16 + ci) * IPIX;
        float v0 = xp[0];
        float v1 = xp[16 * IPIX];
        float v2 = xp[32 * IPIX];
        float v3 = xp[48 * IPIX];
        short4v u;
        u[0] = (short)f2bf(v0); u[1] = (short)f2bf(v1);
        u[2] = (short)f2bf(v2); u[3] = (short)f2bf(v3);
        int chunk = (g0 >> 3) ^ (ci & 7) ^ (px & 7);
        *(short4v*)(smem + px * 2048 + ci * 128 + chunk * 16 + (g0 & 7) * 2) = u;
    }
    __syncthreads();

    // ---- compute ----
    int lane = t & 63, wv = t >> 6;
    int ln = lane & 15, quad = lane >> 4;

    short8 bf[8];
    #pragma unroll
    for (int q8 = 0; q8 < 8; ++q8)
        bf[q8] = *(const short8*)(wmb + (q8 * 64 + lane) * 8);  // [jt*2+kh]

    unsigned short* Zb = Z + (size_t)(b * IPIX + p0) * 1024;
    for (int k = 0; k < 8; ++k) {
        int pl = wv * 8 + k;
        const char* arow = smem + pl * 2048 + ln * 128;
        int sw = (ln & 7) ^ (pl & 7);
        short8 a0 = *(const short8*)(arow + (((0 + quad) ^ sw) * 16));
        short8 a1 = *(const short8*)(arow + (((4 + quad) ^ sw) * 16));
        unsigned short* zp = Zb + (size_t)pl * 1024 + ln * 16 + quad * 4;
        #pragma unroll
        for (int jt = 0; jt < 4; ++jt) {
            float4v acc = {0.f, 0.f, 0.f, 0.f};
            acc = __builtin_amdgcn_mfma_f32_16x16x32_bf16(a0, bf[jt * 2 + 0], acc, 0, 0, 0);
            acc = __builtin_amdgcn_mfma_f32_16x16x32_bf16(a1, bf[jt * 2 + 1], acc, 0, 0, 0);
            short4v o;
            o[0] = (short)f2bf(acc[0]); o[1] = (short)f2bf(acc[1]);
            o[2] = (short)f2bf(acc[2]); o[3] = (short)f2bf(acc[3]);
            *(short4v*)(zp + jt * 256) = o;
        }
    }
}

// ---------------------------------------------------------------------------
// conv2: out[b,c0,p,j] = bias[j] + sum_{ci,tap} K[c0,ci,tap] * Z[b, p+tap, j, ci]
// MFMA: D[m=c0][n=j-tile], K-dim = 160 (9 taps x 16 ci, padded) = 5 frags.
// B-frags read straight from global Z (L1 covers the 9-tap slide reuse).
// grid = 8 * 62 * 2 = 992 blocks of 256; wave = j-tile, covers 31 pixels.
// ---------------------------------------------------------------------------
__global__ __launch_bounds__(256, 4) void conv2_kernel(const unsigned short* __restrict__ Z,
                                                       const unsigned short* __restrict__ kb,
                                                       const float* __restrict__ bias,
                                                       float* __restrict__ out) {
    int t = threadIdx.x, lane = t & 63, wv = t >> 6;
    int ln = lane & 15, quad = lane >> 4;
    int blk = blockIdx.x;
    int xh = blk & 1;
    int y  = (blk >> 1) % OH;
    int b  = blk / (OH * 2);

    short8 af[5];
    int off[5];
    #pragma unroll
    for (int f = 0; f < 5; ++f) {
        af[f] = *(const short8*)(kb + (f * 64 + lane) * 8);
        int tap = f * 2 + (quad >> 1);
        if (tap > 8) tap = 8;              // pad chunk: A is zero, any valid addr
        int dy = tap / 3, dx = tap % 3;
        off[f] = (dy * IW + dx) * 1024 + (wv * 16 + ln) * 16 + (quad & 1) * 8;
    }
    float bv = bias[wv * 16 + ln];

    const unsigned short* zbase = Z + (size_t)(b * IPIX + y * IW + xh * 31) * 1024;
    float* ob = out + ((size_t)(b * NC0) * OPIX + (size_t)(y * OW + xh * 31)) * NJ
                    + wv * 16 + ln;

    #pragma unroll 2
    for (int xi = 0; xi < 31; ++xi) {
        const unsigned short* zp = zbase + (size_t)xi * 1024;
        short8 z0 = *(const short8*)(zp + off[0]);
        short8 z1 = *(const short8*)(zp + off[1]);
        short8 z2 = *(const short8*)(zp + off[2]);
        short8 z3 = *(const short8*)(zp + off[3]);
        short8 z4 = *(const short8*)(zp + off[4]);
        float4v acc = {bv, bv, bv, bv};
        acc = __builtin_amdgcn_mfma_f32_16x16x32_bf16(af[0], z0, acc, 0, 0, 0);
        acc = __builtin_amdgcn_mfma_f32_16x16x32_bf16(af[1], z1, acc, 0, 0, 0);
        acc = __builtin_amdgcn_mfma_f32_16x16x32_bf16(af[2], z2, acc, 0, 0, 0);
        acc = __builtin_amdgcn_mfma_f32_16x16x32_bf16(af[3], z3, acc, 0, 0, 0);
        acc = __builtin_amdgcn_mfma_f32_16x16x32_bf16(af[4], z4, acc, 0, 0, 0);
        float* op = ob + (size_t)xi * NJ;
        #pragma unroll
        for (int r = 0; r < 4; ++r) {
            op[(size_t)(quad * 4 + r) * OPIX * NJ] = acc[r];
        }
    }
}

// ---------------------------------------------------------------------------
// Fallback path (small ws): round-1 kernels, fp32 throughout.
// ---------------------------------------------------------------------------
__global__ __launch_bounds__(64) void wm_kernel(const float* __restrict__ core0,
                                                const float* __restrict__ core1,
                                                const float* __restrict__ core2,
                                                float* __restrict__ Wm) {
    int g = threadIdx.x;
    int i1 = g >> 4, i2 = (g >> 2) & 3, i3 = g & 3;
    for (int j = 0; j < NJ; ++j) {
        int j1 = j >> 4, j2 = (j >> 2) & 3, j3 = j & 3;
        float s = 0.f;
        #pragma unroll
        for (int r1 = 0; r1 < 8; ++r1) {
            float a = core0[(i1 * 4 + j1) * 8 + r1];
            float t = 0.f;
            #pragma unroll
            for (int r2 = 0; r2 < 8; ++r2) {
                t += core1[((r1 * 4 + i2) * 4 + j2) * 8 + r2] *
                     core2[(r2 * 4 + i3) * 4 + j3];
            }
            s += a * t;
        }
        Wm[g * NJ + j] = s;
    }
}

__global__ __launch_bounds__(256) void fused_fallback(const float* __restrict__ x,
                                                      const float* __restrict__ K,
                                                      const float* __restrict__ Wm,
                                                      const float* __restrict__ bias,
                                                      float* __restrict__ out) {
    __shared__ float wlds[NG * NJ];
    __shared__ float klds[NCI * 9];
    int blk  = blockIdx.x;
    int pblk = blk & 15;
    int c0   = (blk >> 4) & 15;
    int b    = blk >> 8;
    for (int i = threadIdx.x; i < NG * NJ; i += 256) wlds[i] = Wm[i];
    for (int i = threadIdx.x; i < NCI * 9; i += 256) klds[i] = K[c0 * NCI * 9 + i];
    __syncthreads();

    int pix = pblk * 256 + threadIdx.x;
    if (pix >= OPIX) return;
    int y  = pix / OW;
    int xx = pix % OW;

    float acc[NJ];
    #pragma unroll
    for (int j = 0; j < NJ; ++j) acc[j] = 0.f;

    for (int g = 0; g < NG; ++g) {
        float c = 0.f;
        const float* xb = x + ((size_t)(b * NG + g) * NCI) * IPIX;
        for (int ci = 0; ci < NCI; ++ci) {
            #pragma unroll
            for (int dy = 0; dy < 3; ++dy) {
                #pragma unroll
                for (int dx = 0; dx < 3; ++dx) {
                    c += xb[ci * IPIX + (y + dy) * IW + (xx + dx)] *
                         klds[ci * 9 + dy * 3 + dx];
                }
            }
        }
        const float4* wp = (const float4*)&wlds[g * NJ];
        #pragma unroll
        for (int j4 = 0; j4 < 16; ++j4) {
            float4 w = wp[j4];
            acc[j4 * 4 + 0] += w.x * c;
            acc[j4 * 4 + 1] += w.y * c;
            acc[j4 * 4 + 2] += w.z * c;
            acc[j4 * 4 + 3] += w.w * c;
        }
    }
    #pragma unroll
    for (int j = 0; j < NJ; ++j) {
        out[(((size_t)(b * NC0 + c0) * OPIX) + pix) * NJ + j] = acc[j] + bias[j];
    }
}

extern "C" void kernel_launch(void* const* d_in, const int* in_sizes, int n_in,
                              void* d_out, int out_size, void* d_ws, size_t ws_size,
                              hipStream_t stream) {
    const float* x     = (const float*)d_in[0];
    const float* K     = (const float*)d_in[1];
    const float* core0 = (const float*)d_in[2];
    const float* core1 = (const float*)d_in[3];
    const float* core2 = (const float*)d_in[4];
    const float* bias  = (const float*)d_in[5];
    float* out = (float*)d_out;

    const size_t z_off   = 16384;
    const size_t z_bytes = (size_t)NB * IPIX * NJ * NCI * sizeof(unsigned short);  // 67.1 MB

    if (ws_size >= z_off + z_bytes + 256) {
        unsigned short* wmb = (unsigned short*)d_ws;                    // 8 KB
        unsigned short* kb  = (unsigned short*)((char*)d_ws + 8192);    // 5 KB
        unsigned short* Z   = (unsigned short*)((char*)d_ws + z_off);
        prep_kernel<<<9, 64, 0, stream>>>(K, core0, core1, core2, wmb, kb);
        mix2_kernel<<<NB * 128, 256, 0, stream>>>(x, wmb, Z);
        conv2_kernel<<<NB * OH * 2, 256, 0, stream>>>(Z, kb, bias, out);
    } else {
        float* Wm = (float*)d_ws;
        wm_kernel<<<1, 64, 0, stream>>>(core0, core1, core2, Wm);
        fused_fallback<<<NB * NC0 * 16, 256, 0, stream>>>(x, K, Wm, bias, out);
    }
}